// Round 1
// baseline (431.541 us; speedup 1.0000x reference)
//
#include <hip/hip_runtime.h>
#include <stdint.h>

// CoarseMatching on MI355X, round 3.
// conf[n,l,s] = softmax_l(sim)*softmax_s(sim), sim = <f0[l],f1[s]>/25.6.
// |sim| <= ~4 so exp() is safe in fp32 without max subtraction.
// Round-3 change: NO eh intermediate (was a 208MB HBM round-trip).
//   Pass A (GEMM): den_r[l] = sum_s exp(sim), den_c[s] = sum_l exp(sim).
//   Pass B (GEMM, recompute): conf = exp(2*sim)*invdr*invdc written f32
//     directly, with fused row-argmax (12 regs/lane, one reduce at block end)
//     and colmax (LDS partials + atomicMax on positive-float bits).
// Mutual-nearest bit-equality is safe: rowmax/colmax/conf all read the same
// pass-B values.

typedef _Float16 f16;
typedef _Float16 f16x8 __attribute__((ext_vector_type(8)));
typedef float f32x4 __attribute__((ext_vector_type(4)));

#define N_B 4
#define L_DIM 3600
#define S_DIM 3600
#define C_DIM 256

// GEMM tiling (both passes): 3 waves x 48 rows = 144 rows/block; 48 cols/iter;
// 720-col chunks. grid 25 x 5 x 4 = 500 blocks.
#define P1_THREADS 192
#define P1_BM 144
#define P1_BN 48
#define P1_ITERS 15
#define P1_CHUNK 720
#define P1_NCH 5
#define P1_NRT 25        // 3600/144
#define YT_STRIDE 264    // 256 + 8 halfs pad (breaks 16-way LDS bank conflict)

// sim = dot/25.6 ; exp(sim) = exp2(dot * log2e/25.6)
#define C_EXP1 (0.0390625f * 1.4426950408889634f)
// exp(2*sim) = exp2(dot * 2*log2e/25.6)
#define C_EXP2 (0.0781250f * 1.4426950408889634f)

__global__ void cast_kernel(const float* __restrict__ a, const float* __restrict__ b,
                            f16* __restrict__ ah, f16* __restrict__ bh, int total8) {
  int i = blockIdx.x * blockDim.x + threadIdx.x;
  if (i >= total8) return;
  const float4* a4 = (const float4*)a;
  const float4* b4 = (const float4*)b;
  float4 x = a4[2 * (size_t)i], y = a4[2 * (size_t)i + 1];
  f16x8 o = {(f16)x.x, (f16)x.y, (f16)x.z, (f16)x.w,
             (f16)y.x, (f16)y.y, (f16)y.z, (f16)y.w};
  *(f16x8*)(ah + 8 * (size_t)i) = o;
  x = b4[2 * (size_t)i]; y = b4[2 * (size_t)i + 1];
  f16x8 o2 = {(f16)x.x, (f16)x.y, (f16)x.z, (f16)x.w,
              (f16)y.x, (f16)y.y, (f16)y.z, (f16)y.w};
  *(f16x8*)(bh + 8 * (size_t)i) = o2;
}

// Pass A: GEMM computing only the softmax denominators (no big store).
__global__ __launch_bounds__(P1_THREADS) void gemm_stats_kernel(
    const f16* __restrict__ X, const f16* __restrict__ Y,
    float* __restrict__ den_r, float* __restrict__ den_c) {
  __shared__ f16 Yt[P1_BN][YT_STRIDE];
  __shared__ float colsum_w[3][P1_CHUNK];
  const int rt = blockIdx.x, ch = blockIdx.y, n = blockIdx.z;
  const int tid = threadIdx.x;
  const int wave = tid >> 6, lane = tid & 63;
  const int q = lane >> 4, r = lane & 15;
  const int l0 = rt * P1_BM;
  const int s0 = ch * P1_CHUNK;

  // A fragments: 48 rows (3 groups of 16) x K=256 in registers.
  f16x8 a[3][8];
#pragma unroll
  for (int grp = 0; grp < 3; ++grp) {
    const f16* xrow = X + ((size_t)n * L_DIM + l0 + wave * 48 + grp * 16 + r) * C_DIM;
#pragma unroll
    for (int k = 0; k < 8; ++k) a[grp][k] = *(const f16x8*)(xrow + k * 32 + q * 8);
  }

  float sum_e[3][4];
#pragma unroll
  for (int grp = 0; grp < 3; ++grp)
#pragma unroll
    for (int g = 0; g < 4; ++g) sum_e[grp][g] = 0.f;

  for (int it = 0; it < P1_ITERS; ++it) {
    const f16* ysrc = Y + ((size_t)n * S_DIM + s0 + it * P1_BN) * C_DIM;
#pragma unroll
    for (int i = 0; i < 8; ++i) {  // 48*32=1536 16B chunks, 192 thr x 8
      int c = i * P1_THREADS + tid;
      int row = c >> 5, cc = c & 31;
      *(f16x8*)&Yt[row][cc * 8] = *(const f16x8*)(ysrc + row * C_DIM + cc * 8);
    }
    __syncthreads();

    f32x4 acc[3][3];  // [grp][nt]
#pragma unroll
    for (int grp = 0; grp < 3; ++grp)
#pragma unroll
      for (int nt = 0; nt < 3; ++nt) acc[grp][nt] = (f32x4){0.f, 0.f, 0.f, 0.f};

#pragma unroll
    for (int k = 0; k < 8; ++k) {
#pragma unroll
      for (int nt = 0; nt < 3; ++nt) {
        f16x8 b = *(const f16x8*)&Yt[nt * 16 + r][k * 32 + q * 8];
#pragma unroll
        for (int grp = 0; grp < 3; ++grp)
          acc[grp][nt] = __builtin_amdgcn_mfma_f32_16x16x32_f16(a[grp][k], b, acc[grp][nt], 0, 0, 0);
      }
    }
    __syncthreads();

    // epilogue: C/D layout col=lane&15, row=(lane>>4)*4+reg
#pragma unroll
    for (int nt = 0; nt < 3; ++nt) {
      float csum = 0.f;
#pragma unroll
      for (int grp = 0; grp < 3; ++grp) {
#pragma unroll
        for (int g = 0; g < 4; ++g) {
          float e = exp2f(acc[grp][nt][g] * C_EXP1);
          sum_e[grp][g] += e;
          csum += e;
        }
      }
      csum += __shfl_xor(csum, 16, 64);
      csum += __shfl_xor(csum, 32, 64);
      if (q == 0) colsum_w[wave][it * P1_BN + nt * 16 + r] = csum;
    }
  }

  // row sums: reduce over the 16 s-lanes
#pragma unroll
  for (int m = 1; m < 16; m <<= 1)
#pragma unroll
    for (int grp = 0; grp < 3; ++grp)
#pragma unroll
      for (int g = 0; g < 4; ++g) sum_e[grp][g] += __shfl_xor(sum_e[grp][g], m, 64);
  if (r == 0) {
#pragma unroll
    for (int grp = 0; grp < 3; ++grp)
#pragma unroll
      for (int g = 0; g < 4; ++g)
        atomicAdd(&den_r[n * L_DIM + l0 + wave * 48 + grp * 16 + q * 4 + g], sum_e[grp][g]);
  }

  __syncthreads();
  for (int i = tid; i < P1_CHUNK; i += P1_THREADS)
    atomicAdd(&den_c[n * S_DIM + s0 + i],
              colsum_w[0][i] + colsum_w[1][i] + colsum_w[2][i]);
}

__global__ void invert_kernel(float* __restrict__ a, float* __restrict__ b) {
  int i = blockIdx.x * blockDim.x + threadIdx.x;
  if (i >= N_B * L_DIM) return;
  a[i] = 1.0f / a[i];
  b[i] = 1.0f / b[i];
}

// Pass B: recompute GEMM, write conf f32 directly, fused row-argmax + colmax.
__global__ __launch_bounds__(P1_THREADS) void gemm_conf_kernel(
    const f16* __restrict__ X, const f16* __restrict__ Y,
    const float* __restrict__ invdr, const float* __restrict__ invdc,
    float* __restrict__ conf_out,
    unsigned long long* __restrict__ rowarg,
    unsigned int* __restrict__ colmax_bits) {
  __shared__ f16 Yt[P1_BN][YT_STRIDE];
  __shared__ float colmax_w[3][P1_CHUNK];
  const int rt = blockIdx.x, ch = blockIdx.y, n = blockIdx.z;
  const int tid = threadIdx.x;
  const int wave = tid >> 6, lane = tid & 63;
  const int q = lane >> 4, r = lane & 15;
  const int l0 = rt * P1_BM;
  const int s0 = ch * P1_CHUNK;

  f16x8 a[3][8];
#pragma unroll
  for (int grp = 0; grp < 3; ++grp) {
    const f16* xrow = X + ((size_t)n * L_DIM + l0 + wave * 48 + grp * 16 + r) * C_DIM;
#pragma unroll
    for (int k = 0; k < 8; ++k) a[grp][k] = *(const f16x8*)(xrow + k * 32 + q * 8);
  }

  // per-lane inverse row denominators for the 12 rows this lane owns
  float idr[3][4];
#pragma unroll
  for (int grp = 0; grp < 3; ++grp)
#pragma unroll
    for (int g = 0; g < 4; ++g)
      idr[grp][g] = invdr[n * L_DIM + l0 + wave * 48 + grp * 16 + q * 4 + g];

  // running row argmax, 12 rows/lane; cols ascend within lane so strict >
  // keeps the smallest j (matches argmax-first semantics)
  float mx[12];
  int mj[12];
#pragma unroll
  for (int i = 0; i < 12; ++i) { mx[i] = 0.f; mj[i] = 0; }

  float* cbase = conf_out + ((size_t)n * L_DIM + l0 + wave * 48) * S_DIM;

  for (int it = 0; it < P1_ITERS; ++it) {
    const f16* ysrc = Y + ((size_t)n * S_DIM + s0 + it * P1_BN) * C_DIM;
#pragma unroll
    for (int i = 0; i < 8; ++i) {
      int c = i * P1_THREADS + tid;
      int row = c >> 5, cc = c & 31;
      *(f16x8*)&Yt[row][cc * 8] = *(const f16x8*)(ysrc + row * C_DIM + cc * 8);
    }
    __syncthreads();

    f32x4 acc[3][3];
#pragma unroll
    for (int grp = 0; grp < 3; ++grp)
#pragma unroll
      for (int nt = 0; nt < 3; ++nt) acc[grp][nt] = (f32x4){0.f, 0.f, 0.f, 0.f};

#pragma unroll
    for (int k = 0; k < 8; ++k) {
#pragma unroll
      for (int nt = 0; nt < 3; ++nt) {
        f16x8 b = *(const f16x8*)&Yt[nt * 16 + r][k * 32 + q * 8];
#pragma unroll
        for (int grp = 0; grp < 3; ++grp)
          acc[grp][nt] = __builtin_amdgcn_mfma_f32_16x16x32_f16(a[grp][k], b, acc[grp][nt], 0, 0, 0);
      }
    }
    __syncthreads();

#pragma unroll
    for (int nt = 0; nt < 3; ++nt) {
      const int scol = s0 + it * P1_BN + nt * 16 + r;
      const float idc = invdc[n * S_DIM + scol];
      float cm = 0.f;
#pragma unroll
      for (int grp = 0; grp < 3; ++grp) {
#pragma unroll
        for (int g = 0; g < 4; ++g) {
          float w = exp2f(acc[grp][nt][g] * C_EXP2) * idr[grp][g] * idc;
          cbase[(size_t)(grp * 16 + q * 4 + g) * S_DIM + scol] = w;
          const int idx = grp * 4 + g;
          if (w > mx[idx]) { mx[idx] = w; mj[idx] = scol; }
          cm = fmaxf(cm, w);
        }
      }
      cm = fmaxf(cm, __shfl_xor(cm, 16, 64));
      cm = fmaxf(cm, __shfl_xor(cm, 32, 64));
      if (q == 0) colmax_w[wave][it * P1_BN + nt * 16 + r] = cm;
    }
  }

  // row argmax: reduce across the 16 r-lanes (bits 0-3), once per block
#pragma unroll
  for (int m = 1; m < 16; m <<= 1) {
#pragma unroll
    for (int idx = 0; idx < 12; ++idx) {
      float ov = __shfl_xor(mx[idx], m, 64);
      int oj = __shfl_xor(mj[idx], m, 64);
      if (ov > mx[idx] || (ov == mx[idx] && oj < mj[idx])) { mx[idx] = ov; mj[idx] = oj; }
    }
  }
  if (r == 0) {
#pragma unroll
    for (int grp = 0; grp < 3; ++grp) {
#pragma unroll
      for (int g = 0; g < 4; ++g) {
        const int idx = grp * 4 + g;
        unsigned long long key =
            ((unsigned long long)__float_as_uint(mx[idx]) << 32) |
            (unsigned int)(~(unsigned int)mj[idx]);
        atomicMax(&rowarg[n * L_DIM + l0 + wave * 48 + grp * 16 + q * 4 + g], key);
      }
    }
  }

  __syncthreads();
  // colmax: merge the 3 wave partials, one atomic per column per block
  for (int i = tid; i < P1_CHUNK; i += P1_THREADS) {
    float m3 = fmaxf(fmaxf(colmax_w[0][i], colmax_w[1][i]), colmax_w[2][i]);
    atomicMax(&colmax_bits[n * S_DIM + s0 + i], __float_as_uint(m3));
  }
}

__global__ void finalize_kernel(const unsigned long long* __restrict__ rowarg,
                                const float* __restrict__ colmax,
                                const int* __restrict__ h0c, const int* __restrict__ w0c,
                                const int* __restrict__ h1c, const int* __restrict__ w1c,
                                float* __restrict__ out_maskv, float* __restrict__ out_jids,
                                float* __restrict__ out_mconf) {
  int i = blockIdx.x * blockDim.x + threadIdx.x;
  if (i >= N_B * L_DIM) return;
  int n = i / L_DIM, l = i - n * L_DIM;
  unsigned long long key = rowarg[i];
  float rm = __uint_as_float((unsigned int)(key >> 32));
  int j = (int)(~(unsigned int)key);
  int W0 = *w0c, H0 = *h0c, W1 = *w1c, H1 = *h1c;
  int li = l / W0, lj = l - li * W0;
  bool vl = (li >= 2) && (li < H0 - 2) && (lj >= 2) && (lj < W0 - 2);
  int si = j / W1, sj = j - si * W1;
  bool vs = (si >= 2) && (si < H1 - 2) && (sj >= 2) && (sj < W1 - 2);
  float cm = colmax[n * S_DIM + j];
  bool mv = (rm > 0.2f) && vl && vs &&
            (__float_as_uint(rm) == __float_as_uint(cm));
  out_maskv[i] = mv ? 1.0f : 0.0f;
  out_jids[i]  = mv ? (float)j : 0.0f;
  out_mconf[i] = mv ? rm : 0.0f;
}

extern "C" void kernel_launch(void* const* d_in, const int* in_sizes, int n_in,
                              void* d_out, int out_size, void* d_ws, size_t ws_size,
                              hipStream_t stream) {
  const float* f0 = (const float*)d_in[0];
  const float* f1 = (const float*)d_in[1];
  const int* h0c = (const int*)d_in[2];
  const int* w0c = (const int*)d_in[3];
  const int* h1c = (const int*)d_in[4];
  const int* w1c = (const int*)d_in[5];

  char* ws = (char*)d_ws;
  size_t o = 0;
  f16* f0h = (f16*)(ws + o);               o += (size_t)N_B * L_DIM * C_DIM * 2;   // 7.37MB
  f16* f1h = (f16*)(ws + o);               o += (size_t)N_B * S_DIM * C_DIM * 2;   // 7.37MB
  // zeroed region (one memset): den_r | den_c | rowarg | colmax
  float* den_r = (float*)(ws + o);         o += (size_t)N_B * L_DIM * 4;
  float* den_c = (float*)(ws + o);         o += (size_t)N_B * S_DIM * 4;
  unsigned long long* rowarg = (unsigned long long*)(ws + o); o += (size_t)N_B * L_DIM * 8;
  float* colmax = (float*)(ws + o);        o += (size_t)N_B * S_DIM * 4;
  size_t zero_bytes = (size_t)N_B * (L_DIM * 4 + S_DIM * 4 + L_DIM * 8 + S_DIM * 4);

  float* conf = (float*)d_out;
  float* out_maskv = conf + (size_t)N_B * L_DIM * S_DIM;
  float* out_jids = out_maskv + N_B * L_DIM;
  float* out_mconf = out_jids + N_B * L_DIM;

  hipMemsetAsync(den_r, 0, zero_bytes, stream);

  int total8 = N_B * L_DIM * C_DIM / 8;  // 460800
  cast_kernel<<<dim3((total8 + 255) / 256), 256, 0, stream>>>(f0, f1, f0h, f1h, total8);

  dim3 g1(P1_NRT, P1_NCH, N_B);  // 25 x 5 x 4 = 500 blocks
  gemm_stats_kernel<<<g1, P1_THREADS, 0, stream>>>(f0h, f1h, den_r, den_c);
  invert_kernel<<<(N_B * L_DIM + 255) / 256, 256, 0, stream>>>(den_r, den_c);
  gemm_conf_kernel<<<g1, P1_THREADS, 0, stream>>>(
      f0h, f1h, den_r, den_c, conf, rowarg, (unsigned int*)colmax);
  finalize_kernel<<<(N_B * L_DIM + 255) / 256, 256, 0, stream>>>(
      rowarg, colmax, h0c, w0c, h1c, w1c, out_maskv, out_jids, out_mconf);
}